// Round 2
// baseline (204.283 us; speedup 1.0000x reference)
//
#include <hip/hip_runtime.h>
#include <hip/hip_bf16.h>

// streams: x250 (len 15000, step 4), x500 (len 30000, step 2), x1000 (len 60000, step 1)
// L = 60000, D_MODEL = 256, KERNEL = 5 taps, pad = 2. Inputs fp32, output fp32.
// Output (flat fp32): X [3,256,60000] = 46,080,000 elems; S [2,60000] = 120,000.
// Conv collapses per stream (zero-insertion upsample):
//   i=0: y = b + w2*x[p]                           (p<15000)
//   i=1: y = b + w0*x[p-1] + w2*x[p] + w4*x[p+1]   (p<30000)
//   i=2: full 5-tap                                (p<60000)
//
// R2 restructure: fill-shaped store stream. Previous kernel wrote 32 scattered
// 4KB segments per block (240KB channel stride per step) and achieved only
// ~2.4 TB/s; the harness fill kernel proves 6.7 TB/s on this buffer with a
// linear sweep. Now: one block per HALF output row (120KB), stores walk the
// row linearly and coalesced. x comes from L1/L2 (streams are <=240KB,
// cache-resident); W/b are block-uniform -> scalar loads once per block.
// i=0/i=1 upper halves are pure-zero blocks (no loads at all).

#define L_OUT   60000
#define LEN0    15000
#define LEN1    30000
#define LEN2    60000
#define DMODEL  256
#define X_ELEMS (3 * DMODEL * L_OUT)
#define HALF4   7500          // float4s per half row (30000 floats)

typedef float float4v __attribute__((ext_vector_type(4)));

__device__ __forceinline__ void st4(float* p, float a, float b, float c, float d) {
    float4v v; v.x = a; v.y = b; v.z = c; v.w = d;
    *(float4v*)p = v;
}

// grid: 1536 conv blocks (row = bid>>1, half = bid&1) + 30 S blocks. 256 thr.
__global__ __launch_bounds__(256) void embed_kernel(
    const float* __restrict__ x250,
    const float* __restrict__ x500,
    const float* __restrict__ x1000,
    const float* __restrict__ W,   // [256,1,5]
    const float* __restrict__ b,   // [256]
    float* __restrict__ out)
{
    const int bid = blockIdx.x;
    const int tid = threadIdx.x;

    if (bid >= 1536) {
        // ---- S duty: 30 blocks x 1024 float4 cover 30000 float4s ----
        const int s = bid - 1536;
        const int base = s * 1024;
#pragma unroll
        for (int j = 0; j < 4; ++j) {
            const int q4 = base + j * 256 + tid;
            if (q4 < 30000) {
                float ov[4];
#pragma unroll
                for (int k = 0; k < 4; ++k) {
                    const int e = q4 * 4 + k;
                    float val;
                    if (e < L_OUT) {
                        val = (e < 15000) ? 0.0f : ((e < 45000) ? 1.0f : 2.0f);
                    } else {
                        const int u = e - L_OUT;
                        int iv;
                        if (u < 15000)      iv = 4 * u;
                        else if (u < 45000) iv = 2 * (u - 15000);
                        else                iv = u - 45000;
                        val = (float)iv;
                    }
                    ov[k] = val;
                }
                st4(out + X_ELEMS + q4 * 4, ov[0], ov[1], ov[2], ov[3]);
            }
        }
        return;
    }

    const int row  = bid >> 1;       // 0..767  (= i*256 + c)
    const int half = bid & 1;        // 0: first 30000 floats, 1: second
    const int i    = row >> 8;       // stream
    const int c    = row & 255;      // channel

    float* __restrict__ dstrow = out + (size_t)row * L_OUT;

    // pure-zero halves: i=0 and i=1 have no live samples past p=30000
    if (half == 1 && i != 2) {
        float* d = dstrow + 30000;
        for (int p4l = tid; p4l < HALF4; p4l += 256)
            st4(d + p4l * 4, 0.f, 0.f, 0.f, 0.f);
        return;
    }

    // block-uniform weights -> scalar loads, once
    const float w0 = W[c * 5 + 0], w1 = W[c * 5 + 1], w2 = W[c * 5 + 2],
                w3 = W[c * 5 + 3], w4 = W[c * 5 + 4], bias = b[c];

    if (i == 0) {
        // half == 0 only: live p4 < 3750, zeros for p4 in [3750,7500)
        const float4v* __restrict__ x4 = (const float4v*)x250;
        for (int p4 = tid; p4 < HALF4; p4 += 256) {
            if (p4 < 3750) {
                const float4v xv = x4[p4];
                st4(dstrow + p4 * 4,
                    fmaf(w2, xv.x, bias), fmaf(w2, xv.y, bias),
                    fmaf(w2, xv.z, bias), fmaf(w2, xv.w, bias));
            } else {
                st4(dstrow + p4 * 4, 0.f, 0.f, 0.f, 0.f);
            }
        }
    } else if (i == 1) {
        // half == 0 only: all 7500 float4s live (p0 < 30000)
        const float4v* __restrict__ x4 = (const float4v*)x500;
        const float4v z4 = {0.f, 0.f, 0.f, 0.f};
        for (int p4 = tid; p4 < HALF4; p4 += 256) {
            const float4v lo  = (p4 > 0)    ? x4[p4 - 1] : z4;
            const float4v mid = x4[p4];
            const float4v hi  = (p4 < 7499) ? x4[p4 + 1] : z4;
            // window floats 4p4-1 .. 4p4+4 = {lo.w, mid.x..w, hi.x}
            float y0 = fmaf(w0, lo.w,  bias); y0 = fmaf(w2, mid.x, y0); y0 = fmaf(w4, mid.y, y0);
            float y1 = fmaf(w0, mid.x, bias); y1 = fmaf(w2, mid.y, y1); y1 = fmaf(w4, mid.z, y1);
            float y2 = fmaf(w0, mid.y, bias); y2 = fmaf(w2, mid.z, y2); y2 = fmaf(w4, mid.w, y2);
            float y3 = fmaf(w0, mid.z, bias); y3 = fmaf(w2, mid.w, y3); y3 = fmaf(w4, hi.x,  y3);
            st4(dstrow + p4 * 4, y0, y1, y2, y3);
        }
    } else {
        // full 5-tap, both halves live; p4 is GLOBAL float4 index in the row
        const float4v* __restrict__ x4 = (const float4v*)x1000;
        const float4v z4 = {0.f, 0.f, 0.f, 0.f};
        const int p4base = half * HALF4;
        for (int p4l = tid; p4l < HALF4; p4l += 256) {
            const int p4 = p4base + p4l;
            const float4v lo  = (p4 > 0)     ? x4[p4 - 1] : z4;
            const float4v mid = x4[p4];
            const float4v hi  = (p4 < 14999) ? x4[p4 + 1] : z4;
            // window floats 4p4-2 .. 4p4+5 = {lo.z, lo.w, mid.x..w, hi.x, hi.y}
            float y0 = fmaf(w0, lo.z,  bias); y0 = fmaf(w1, lo.w,  y0);
            y0 = fmaf(w2, mid.x, y0);  y0 = fmaf(w3, mid.y, y0);  y0 = fmaf(w4, mid.z, y0);
            float y1 = fmaf(w0, lo.w,  bias); y1 = fmaf(w1, mid.x, y1);
            y1 = fmaf(w2, mid.y, y1);  y1 = fmaf(w3, mid.z, y1);  y1 = fmaf(w4, mid.w, y1);
            float y2 = fmaf(w0, mid.x, bias); y2 = fmaf(w1, mid.y, y2);
            y2 = fmaf(w2, mid.z, y2);  y2 = fmaf(w3, mid.w, y2);  y2 = fmaf(w4, hi.x,  y2);
            float y3 = fmaf(w0, mid.y, bias); y3 = fmaf(w1, mid.z, y3);
            y3 = fmaf(w2, mid.w, y3);  y3 = fmaf(w3, hi.x,  y3);  y3 = fmaf(w4, hi.y,  y3);
            st4(dstrow + p4 * 4, y0, y1, y2, y3);
        }
    }
}

extern "C" void kernel_launch(void* const* d_in, const int* in_sizes, int n_in,
                              void* d_out, int out_size, void* d_ws, size_t ws_size,
                              hipStream_t stream) {
    const float* x250  = (const float*)d_in[0];
    const float* x500  = (const float*)d_in[1];
    const float* x1000 = (const float*)d_in[2];
    const float* W     = (const float*)d_in[3];
    const float* b     = (const float*)d_in[4];
    float* out = (float*)d_out;

    // 1536 conv half-row blocks + 30 S blocks
    dim3 grid(1566, 1, 1);
    embed_kernel<<<grid, 256, 0, stream>>>(x250, x500, x1000, W, b, out);
}

// Round 3
// 188.420 us; speedup vs baseline: 1.0842x; 1.0842x over previous
//
#include <hip/hip_runtime.h>
#include <hip/hip_bf16.h>

// streams: x250 (len 15000, step 4), x500 (len 30000, step 2), x1000 (len 60000, step 1)
// L = 60000, D_MODEL = 256, KERNEL = 5 taps, pad = 2. Inputs fp32, output fp32.
// Output (flat fp32): X [3,256,60000] = 46,080,000 elems; S [2,60000] = 120,000.
// Conv collapses per stream (zero-insertion upsample):
//   i=0: y = b + w2*x[p]                           (p<15000)
//   i=1: y = b + w0*x[p-1] + w2*x[p] + w4*x[p+1]   (p<30000)
//   i=2: full 5-tap                                (p<60000)
//
// R3: revert to the R1 channel-amortized structure (best measured: embed
// ~77us) after R2's fill-shaped layout regressed to ~93us (load latency in
// the inner loop + heavy-block tail). Model: embed is drain-bound — the
// harness poison fill leaves ~288MB dirty in L2/L3 that drains during our
// kernel; floor ~= (288MB + 185MB victim traffic)/6.7TB/s ~= 70us.
// R3 refinements over R1: (1) heavy-first 1D block ordering — compute
// blocks run while drain contention is highest, pure-zero-fill blocks last;
// (2) dead blocks trimmed (S: 177->118; zero regions dispatched directly).

#define L_OUT   60000
#define LEN0    15000
#define LEN1    30000
#define LEN2    60000
#define DMODEL  256
#define X_ELEMS (3 * DMODEL * L_OUT)

typedef float float4v __attribute__((ext_vector_type(4)));

__device__ __forceinline__ void st4(float* p, float a, float b, float c, float d) {
    float4v v; v.x = a; v.y = b; v.z = c; v.w = d;
    *(float4v*)p = v;
}

__device__ __forceinline__ float ld_or_zero(const float* __restrict__ x,
                                            int idx, int len) {
    return (idx >= 0 && idx < len) ? x[idx] : 0.0f;
}

// 1D grid, heavy-first ordering. Each conv block: 1024 positions x 32 channels.
//   [   0,  472): i=2 live,  cg=bid/59,        chunk=bid%59        (0..58)
//   [ 472,  712): i=1 live,  r/30 -> cg,       chunk=r%30          (0..29)
//   [ 712,  832): i=0 live,  r/15 -> cg,       chunk=r%15          (0..14)
//   [ 832, 1064): i=1 zero,  r/29 -> cg,       chunk=30+r%29       (30..58)
//   [1064, 1416): i=0 zero,  r/44 -> cg,       chunk=15+r%44       (15..58)
//   [1416, 1534): S duty, sid = bid-1416, 118 blocks cover 120000 elems
__global__ __launch_bounds__(256) void embed_kernel(
    const float* __restrict__ x250,
    const float* __restrict__ x500,
    const float* __restrict__ x1000,
    const float* __restrict__ W,   // [256,1,5]
    const float* __restrict__ b,   // [256]
    float* __restrict__ out)
{
    const int bid = blockIdx.x;
    const int tid = threadIdx.x;

    if (bid >= 1416) {
        // ---- S duty: 118 blocks x 1024 floats ----
        const int t0 = (bid - 1416) * 1024 + tid * 4;
        if (t0 >= 2 * L_OUT) return;
        float ov[4];
#pragma unroll
        for (int j = 0; j < 4; ++j) {
            const int t = t0 + j;
            float val;
            if (t < L_OUT) {
                val = (t < 15000) ? 0.0f : ((t < 45000) ? 1.0f : 2.0f);  // rows
            } else {
                const int u = t - L_OUT;                                 // cols
                int iv;
                if (u < 15000)      iv = 4 * u;
                else if (u < 45000) iv = 2 * (u - 15000);
                else                iv = u - 45000;
                val = (float)iv;
            }
            ov[j] = val;
        }
        st4(out + X_ELEMS + t0, ov[0], ov[1], ov[2], ov[3]);
        return;
    }

    int i, cg, chunk;
    bool zero_duty = false;
    if (bid < 472)       { i = 2; cg = bid / 59;  chunk = bid % 59; }
    else if (bid < 712)  { const int r = bid - 472;  i = 1; cg = r / 30; chunk = r % 30; }
    else if (bid < 832)  { const int r = bid - 712;  i = 0; cg = r / 15; chunk = r % 15; }
    else if (bid < 1064) { const int r = bid - 832;  i = 1; cg = r / 29; chunk = 30 + r % 29; zero_duty = true; }
    else                 { const int r = bid - 1064; i = 0; cg = r / 44; chunk = 15 + r % 44; zero_duty = true; }

    const int p0 = chunk * 1024 + tid * 4;
    if (p0 >= L_OUT) return;        // only chunk-58 tail threads

    const int cbase = cg * 32;
    float* dst = out + (size_t)(i * DMODEL + cbase) * L_OUT + p0;
    const int len = (i == 0) ? LEN0 : (i == 1) ? LEN1 : LEN2;

    if (zero_duty || p0 >= len) {
        // ---- pure-zero duty (42% of X bytes): no loads, 32 stores ----
#pragma unroll 4
        for (int ci = 0; ci < 32; ++ci) { st4(dst, 0.f, 0.f, 0.f, 0.f); dst += L_OUT; }
        return;
    }
    // NOTE: len is a multiple of 4 and p0 is a multiple of 4, so p0 < len
    // implies p0+3 < len — no per-position masking needed below.

    if (i == 0) {
        float xv[4];
#pragma unroll
        for (int j = 0; j < 4; ++j) xv[j] = x250[p0 + j];
#pragma unroll 4
        for (int ci = 0; ci < 32; ++ci) {
            const int c = cbase + ci;
            const float w2 = W[c * 5 + 2], bias = b[c];
            float y[4];
#pragma unroll
            for (int j = 0; j < 4; ++j) y[j] = fmaf(w2, xv[j], bias);
            st4(dst, y[0], y[1], y[2], y[3]);
            dst += L_OUT;
        }
    } else if (i == 1) {
        float a[6];                              // x500[p0-1 .. p0+4]
#pragma unroll
        for (int j = 0; j < 6; ++j) a[j] = ld_or_zero(x500, p0 - 1 + j, LEN1);
#pragma unroll 4
        for (int ci = 0; ci < 32; ++ci) {
            const int c = cbase + ci;
            const float w0 = W[c * 5 + 0], w2 = W[c * 5 + 2],
                        w4 = W[c * 5 + 4], bias = b[c];
            float y[4];
#pragma unroll
            for (int j = 0; j < 4; ++j) {
                float acc = fmaf(w0, a[j], bias);     // x[p-1]
                acc = fmaf(w2, a[j + 1], acc);        // x[p]
                acc = fmaf(w4, a[j + 2], acc);        // x[p+1]
                y[j] = acc;
            }
            st4(dst, y[0], y[1], y[2], y[3]);
            dst += L_OUT;
        }
    } else {
        float a[8];                              // x1000[p0-2 .. p0+5]
#pragma unroll
        for (int j = 0; j < 8; ++j) a[j] = ld_or_zero(x1000, p0 - 2 + j, LEN2);
#pragma unroll 4
        for (int ci = 0; ci < 32; ++ci) {
            const int c = cbase + ci;
            const float w0 = W[c * 5 + 0], w1 = W[c * 5 + 1], w2 = W[c * 5 + 2],
                        w3 = W[c * 5 + 3], w4 = W[c * 5 + 4], bias = b[c];
            float y[4];
#pragma unroll
            for (int j = 0; j < 4; ++j) {
                float acc = fmaf(w0, a[j], bias);
                acc = fmaf(w1, a[j + 1], acc);
                acc = fmaf(w2, a[j + 2], acc);
                acc = fmaf(w3, a[j + 3], acc);
                acc = fmaf(w4, a[j + 4], acc);
                y[j] = acc;
            }
            st4(dst, y[0], y[1], y[2], y[3]);
            dst += L_OUT;
        }
    }
}

extern "C" void kernel_launch(void* const* d_in, const int* in_sizes, int n_in,
                              void* d_out, int out_size, void* d_ws, size_t ws_size,
                              hipStream_t stream) {
    const float* x250  = (const float*)d_in[0];
    const float* x500  = (const float*)d_in[1];
    const float* x1000 = (const float*)d_in[2];
    const float* W     = (const float*)d_in[3];
    const float* b     = (const float*)d_in[4];
    float* out = (float*)d_out;

    // 1534 blocks: 472 i=2 + 240 i=1 live + 120 i=0 live
    //            + 232 i=1 zero + 352 i=0 zero + 118 S
    dim3 grid(1534, 1, 1);
    embed_kernel<<<grid, 256, 0, stream>>>(x250, x500, x1000, W, b, out);
}